// Round 6
// baseline (72.630 us; speedup 1.0000x reference)
//
#include <hip/hip_runtime.h>
#include <hip/hip_bf16.h>

typedef short short8 __attribute__((ext_vector_type(8)));
typedef float f32x4 __attribute__((ext_vector_type(4)));

__device__ inline unsigned short f2bf(float f) {
    unsigned u = __builtin_bit_cast(unsigned, f);
    u += 0x7FFFu + ((u >> 16) & 1u);          // round-to-nearest-even
    return (unsigned short)(u >> 16);
}

// ---------------------------------------------------------------------------
// prep: Wm[d][c] = 0.25 * sum_h Wv[h*64+d][c], packed in MFMA B-fragment order:
//   Bf[((ct*8+kc)*64 + lane)*8 + j] = bf16(Wm[ct*16 + lane%16][kc*32 + (lane/16)*8 + j])
// bm[d] = 0.25 * sum_h bv[h*64+d]
// ---------------------------------------------------------------------------
__global__ __launch_bounds__(256)
void k_prep(const float* __restrict__ Wv, const float* __restrict__ bv,
            unsigned short* __restrict__ Bf, float* __restrict__ bm)
{
    const int t = blockIdx.x * 256 + threadIdx.x;   // 0..16383
    const int fi = t >> 9;                          // fragment index 0..31
    const int lane = (t >> 3) & 63;
    const int j = t & 7;
    const int ct = fi >> 3, kc = fi & 7;
    const int d = ct * 16 + (lane & 15);
    const int c = kc * 32 + (lane >> 4) * 8 + j;
    const float s = 0.25f * (Wv[(size_t)d * 256 + c] +
                             Wv[(size_t)(64 + d) * 256 + c] +
                             Wv[(size_t)(128 + d) * 256 + c] +
                             Wv[(size_t)(192 + d) * 256 + c]);
    Bf[t] = f2bf(s);
    if (t < 64)
        bm[t] = 0.25f * (bv[t] + bv[64 + t] + bv[128 + t] + bv[192 + t]);
}

// ---------------------------------------------------------------------------
// main: out[n][d] = sum_c source[n][c] * Wm[d][c] + bm[d]
// 256 threads = 4 waves; each block processes 2 tiles of 64 rows (grid-stride
// by nblk) so tile-1 loads overlap tile-0 store drain (no barriers, no LDS).
// A rows: direct-from-global per-lane fragments, nontemporal (single-use
// stream, keep Bf/bm L2-hot). B fragments: global/L2 (32 KB shared by all).
// ---------------------------------------------------------------------------
__global__ __launch_bounds__(256, 4)
void k_vmean(const float* __restrict__ X, const unsigned short* __restrict__ Bf,
             const float* __restrict__ bm, float* __restrict__ out,
             int N, int ntiles)
{
    const int t = threadIdx.x;
    const int wave = t >> 6, lane = t & 63;
    const int col_lo = lane & 15, kgrp = lane >> 4;

    // bias regs (L2-hot, tiny)
    float bias[4];
#pragma unroll
    for (int ct = 0; ct < 4; ++ct) bias[ct] = bm[ct * 16 + col_lo];

    for (int tile = blockIdx.x; tile < ntiles; tile += gridDim.x) {
        const int rowbase = tile * 64 + wave * 16;
        const int arow0 = rowbase + (lane & 15);
        const int arow = arow0 < N ? arow0 : N - 1;     // clamp tail rows
        const float* xrow = X + (size_t)arow * 256 + kgrp * 8;

        // issue all 16 X loads (8 K-chunks x 32 B per lane) up front, NT
        f32x4 a0[8], a1[8];
#pragma unroll
        for (int kc = 0; kc < 8; ++kc) {
            a0[kc] = __builtin_nontemporal_load((const f32x4*)(xrow + kc * 32));
            a1[kc] = __builtin_nontemporal_load((const f32x4*)(xrow + kc * 32 + 4));
        }

        f32x4 acc[4] = {};
#pragma unroll
        for (int kc = 0; kc < 8; ++kc) {
            short8 a;
            a[0] = (short)f2bf(a0[kc][0]); a[1] = (short)f2bf(a0[kc][1]);
            a[2] = (short)f2bf(a0[kc][2]); a[3] = (short)f2bf(a0[kc][3]);
            a[4] = (short)f2bf(a1[kc][0]); a[5] = (short)f2bf(a1[kc][1]);
            a[6] = (short)f2bf(a1[kc][2]); a[7] = (short)f2bf(a1[kc][3]);
#pragma unroll
            for (int ct = 0; ct < 4; ++ct) {
                const short8 b = *(const short8*)&Bf[((ct * 8 + kc) * 64 + lane) * 8];
                acc[ct] = __builtin_amdgcn_mfma_f32_16x16x32_bf16(a, b, acc[ct], 0, 0, 0);
            }
        }

        // epilogue: C/D layout col = lane&15, row = (lane>>4)*4 + reg  [m89]
        const int orow0 = rowbase + kgrp * 4;
#pragma unroll
        for (int ct = 0; ct < 4; ++ct) {
            const int col = ct * 16 + col_lo;
#pragma unroll
            for (int r = 0; r < 4; ++r) {
                const int row = orow0 + r;
                if (row < N)
                    out[(size_t)row * 64 + col] = acc[ct][r] + bias[ct];
            }
        }
    }
}

extern "C" void kernel_launch(void* const* d_in, const int* in_sizes, int n_in,
                              void* d_out, int out_size, void* d_ws, size_t ws_size,
                              hipStream_t stream)
{
    const float* sx = (const float*)d_in[1];        // source_input
    const float* Wv = (const float*)d_in[6];
    const float* bv = (const float*)d_in[7];
    float* out = (float*)d_out;

    unsigned short* Bf = (unsigned short*)d_ws;                 // 32 KB
    float* bm = (float*)((char*)d_ws + 16384 * sizeof(unsigned short));

    const int N = in_sizes[0] / 256;
    const int ntiles = (N + 63) / 64;
    const int nblk = (ntiles + 1) / 2;              // 2 tiles per block

    k_prep<<<64, 256, 0, stream>>>(Wv, bv, Bf, bm);
    k_vmean<<<nblk, 256, 0, stream>>>(sx, Bf, bm, out, N, ntiles);
}

// Round 7
// 41.769 us; speedup vs baseline: 1.7389x; 1.7389x over previous
//
#include <hip/hip_runtime.h>
#include <hip/hip_bf16.h>

typedef short short8 __attribute__((ext_vector_type(8)));
typedef float f32x4 __attribute__((ext_vector_type(4)));

__device__ inline unsigned short f2bf(float f) {
    unsigned u = __builtin_bit_cast(unsigned, f);
    u += 0x7FFFu + ((u >> 16) & 1u);          // round-to-nearest-even
    return (unsigned short)(u >> 16);
}

// ---------------------------------------------------------------------------
// prep: Wm[d][c] = 0.25 * sum_h Wv[h*64+d][c], packed in MFMA B-fragment order:
//   Bf[((ct*8+kc)*64 + lane)*8 + j] = bf16(Wm[ct*16 + lane%16][kc*32 + (lane/16)*8 + j])
// bm[d] = 0.25 * sum_h bv[h*64+d]
// ---------------------------------------------------------------------------
__global__ __launch_bounds__(256)
void k_prep(const float* __restrict__ Wv, const float* __restrict__ bv,
            unsigned short* __restrict__ Bf, float* __restrict__ bm)
{
    const int t = blockIdx.x * 256 + threadIdx.x;   // 0..16383
    const int fi = t >> 9;                          // fragment index 0..31
    const int lane = (t >> 3) & 63;
    const int j = t & 7;
    const int ct = fi >> 3, kc = fi & 7;
    const int d = ct * 16 + (lane & 15);
    const int c = kc * 32 + (lane >> 4) * 8 + j;
    const float s = 0.25f * (Wv[(size_t)d * 256 + c] +
                             Wv[(size_t)(64 + d) * 256 + c] +
                             Wv[(size_t)(128 + d) * 256 + c] +
                             Wv[(size_t)(192 + d) * 256 + c]);
    Bf[t] = f2bf(s);
    if (t < 64)
        bm[t] = 0.25f * (bv[t] + bv[64 + t] + bv[128 + t] + bv[192 + t]);
}

// ---------------------------------------------------------------------------
// main: out[n][d] = sum_c source[n][c] * Wm[d][c] + bm[d]
// 256 threads = 4 waves. Each block owns TWO 64-row tiles (2b, 2b+1),
// straight-line: issue all 32 A-loads (1 KB/lane in flight), then
// compute+store tile0 (waits only on first 16 loads), then tile1 —
// tile1's loads drain under tile0's MFMA+stores. No LDS, no barriers, no NT.
// B fragments (32 KB, shared by all blocks) stay L2-resident.
// ---------------------------------------------------------------------------
__global__ __launch_bounds__(256)
void k_vmean(const float* __restrict__ X, const unsigned short* __restrict__ Bf,
             const float* __restrict__ bm, float* __restrict__ out,
             int N, int ntiles)
{
    const int t = threadIdx.x;
    const int wave = t >> 6, lane = t & 63;
    const int col_lo = lane & 15, kgrp = lane >> 4;

    const int tile0 = blockIdx.x * 2;
    const int tile1v = tile0 + 1;
    const bool do1 = (tile1v < ntiles);
    const int tile1 = do1 ? tile1v : tile0;

    const int rowbase0 = tile0 * 64 + wave * 16;
    const int rowbase1 = tile1 * 64 + wave * 16;
    const int ar0 = rowbase0 + (lane & 15);
    const int ar1 = rowbase1 + (lane & 15);
    const float* xrow0 = X + (size_t)(ar0 < N ? ar0 : N - 1) * 256 + kgrp * 8;
    const float* xrow1 = X + (size_t)(ar1 < N ? ar1 : N - 1) * 256 + kgrp * 8;

    // issue ALL 32 loads up front (tile0 first — MFMA waits on these only)
    f32x4 p0a[8], p0b[8], p1a[8], p1b[8];
#pragma unroll
    for (int kc = 0; kc < 8; ++kc) {
        p0a[kc] = *(const f32x4*)(xrow0 + kc * 32);
        p0b[kc] = *(const f32x4*)(xrow0 + kc * 32 + 4);
    }
#pragma unroll
    for (int kc = 0; kc < 8; ++kc) {
        p1a[kc] = *(const f32x4*)(xrow1 + kc * 32);
        p1b[kc] = *(const f32x4*)(xrow1 + kc * 32 + 4);
    }

    // bias regs (L2-hot, tiny)
    float bias[4];
#pragma unroll
    for (int ct = 0; ct < 4; ++ct) bias[ct] = bm[ct * 16 + col_lo];

    // ---- tile 0 ----
    f32x4 acc0[4] = {};
#pragma unroll
    for (int kc = 0; kc < 8; ++kc) {
        short8 a;
        a[0] = (short)f2bf(p0a[kc][0]); a[1] = (short)f2bf(p0a[kc][1]);
        a[2] = (short)f2bf(p0a[kc][2]); a[3] = (short)f2bf(p0a[kc][3]);
        a[4] = (short)f2bf(p0b[kc][0]); a[5] = (short)f2bf(p0b[kc][1]);
        a[6] = (short)f2bf(p0b[kc][2]); a[7] = (short)f2bf(p0b[kc][3]);
#pragma unroll
        for (int ct = 0; ct < 4; ++ct) {
            const short8 b = *(const short8*)&Bf[((ct * 8 + kc) * 64 + lane) * 8];
            acc0[ct] = __builtin_amdgcn_mfma_f32_16x16x32_bf16(a, b, acc0[ct], 0, 0, 0);
        }
    }
    const int orow0 = rowbase0 + kgrp * 4;          // C/D: col=lane&15, row=(lane>>4)*4+reg
#pragma unroll
    for (int ct = 0; ct < 4; ++ct) {
        const int col = ct * 16 + col_lo;
#pragma unroll
        for (int r = 0; r < 4; ++r) {
            const int row = orow0 + r;
            if (row < N)
                out[(size_t)row * 64 + col] = acc0[ct][r] + bias[ct];
        }
    }

    // ---- tile 1 ----
    f32x4 acc1[4] = {};
#pragma unroll
    for (int kc = 0; kc < 8; ++kc) {
        short8 a;
        a[0] = (short)f2bf(p1a[kc][0]); a[1] = (short)f2bf(p1a[kc][1]);
        a[2] = (short)f2bf(p1a[kc][2]); a[3] = (short)f2bf(p1a[kc][3]);
        a[4] = (short)f2bf(p1b[kc][0]); a[5] = (short)f2bf(p1b[kc][1]);
        a[6] = (short)f2bf(p1b[kc][2]); a[7] = (short)f2bf(p1b[kc][3]);
#pragma unroll
        for (int ct = 0; ct < 4; ++ct) {
            const short8 b = *(const short8*)&Bf[((ct * 8 + kc) * 64 + lane) * 8];
            acc1[ct] = __builtin_amdgcn_mfma_f32_16x16x32_bf16(a, b, acc1[ct], 0, 0, 0);
        }
    }
    const int orow1 = rowbase1 + kgrp * 4;
#pragma unroll
    for (int ct = 0; ct < 4; ++ct) {
        const int col = ct * 16 + col_lo;
#pragma unroll
        for (int r = 0; r < 4; ++r) {
            const int row = orow1 + r;
            if (do1 && row < N)
                out[(size_t)row * 64 + col] = acc1[ct][r] + bias[ct];
        }
    }
}

extern "C" void kernel_launch(void* const* d_in, const int* in_sizes, int n_in,
                              void* d_out, int out_size, void* d_ws, size_t ws_size,
                              hipStream_t stream)
{
    const float* sx = (const float*)d_in[1];        // source_input
    const float* Wv = (const float*)d_in[6];
    const float* bv = (const float*)d_in[7];
    float* out = (float*)d_out;

    unsigned short* Bf = (unsigned short*)d_ws;                 // 32 KB
    float* bm = (float*)((char*)d_ws + 16384 * sizeof(unsigned short));

    const int N = in_sizes[0] / 256;
    const int ntiles = (N + 63) / 64;
    const int nblk = (ntiles + 1) / 2;              // 2 tiles per block

    k_prep<<<64, 256, 0, stream>>>(Wv, bv, Bf, bm);
    k_vmean<<<nblk, 256, 0, stream>>>(sx, Bf, bm, out, N, ntiles);
}

// Round 8
// 35.619 us; speedup vs baseline: 2.0391x; 1.1726x over previous
//
#include <hip/hip_runtime.h>
#include <hip/hip_bf16.h>

typedef short short8 __attribute__((ext_vector_type(8)));
typedef float f32x4 __attribute__((ext_vector_type(4)));

__device__ inline unsigned short f2bf(float f) {
    unsigned u = __builtin_bit_cast(unsigned, f);
    u += 0x7FFFu + ((u >> 16) & 1u);          // round-to-nearest-even
    return (unsigned short)(u >> 16);
}

__device__ inline void gload_lds16(const void* g, void* l) {
    __builtin_amdgcn_global_load_lds(
        (const __attribute__((address_space(1))) void*)g,
        (__attribute__((address_space(3))) void*)l, 16, 0, 0);
}

// ---------------------------------------------------------------------------
// prep: Wm[d][c] = 0.25 * sum_h Wv[h*64+d][c], packed in MFMA B-fragment order:
//   Bf[((ct*8+kc)*64 + lane)*8 + j] = bf16(Wm[ct*16 + lane%16][kc*32 + (lane/16)*8 + j])
// bm[d] = 0.25 * sum_h bv[h*64+d]
// ---------------------------------------------------------------------------
__global__ __launch_bounds__(256)
void k_prep(const float* __restrict__ Wv, const float* __restrict__ bv,
            unsigned short* __restrict__ Bf, float* __restrict__ bm)
{
    const int t = blockIdx.x * 256 + threadIdx.x;   // 0..16383
    const int fi = t >> 9;                          // fragment index 0..31
    const int lane = (t >> 3) & 63;
    const int j = t & 7;
    const int ct = fi >> 3, kc = fi & 7;
    const int d = ct * 16 + (lane & 15);
    const int c = kc * 32 + (lane >> 4) * 8 + j;
    const float s = 0.25f * (Wv[(size_t)d * 256 + c] +
                             Wv[(size_t)(64 + d) * 256 + c] +
                             Wv[(size_t)(128 + d) * 256 + c] +
                             Wv[(size_t)(192 + d) * 256 + c]);
    Bf[t] = f2bf(s);
    if (t < 64)
        bm[t] = 0.25f * (bv[t] + bv[64 + t] + bv[128 + t] + bv[192 + t]);
}

// ---------------------------------------------------------------------------
// main: out[n][d] = sum_c source[n][c] * Wm[d][c] + bm[d]
// ONE WAVE per block, one 16-row tile. X staged fp32 -> LDS via
// global_load_lds (no VGPR results => allocator cannot sink/serialize the
// batch; all 16 KB in flight). Source pre-swizzled per 16B chunk
// (chunk c of row i -> LDS chunk c ^ (i&7)), LDS dest linear; reads apply
// the same XOR => <=2-way bank aliasing (free). B fragments from L2.
// ---------------------------------------------------------------------------
__global__ __launch_bounds__(64)
void k_vmean(const float* __restrict__ X, const unsigned short* __restrict__ Bf,
             const float* __restrict__ bm, float* __restrict__ out, int N)
{
    __shared__ float Xs[4096];                      // 16 KB: 16 rows x 1 KB
    const int lane = threadIdx.x;
    const int rowbase = blockIdx.x * 16;

    // 1. issue all 16 staging loads (1 KB each, fully coalesced)
#pragma unroll
    for (int i = 0; i < 16; ++i) {
        int row = rowbase + i;
        if (row >= N) row = N - 1;                  // tail clamp (stores masked)
        const char* src = (const char*)(X + (size_t)row * 256)
                        + ((lane * 16) ^ ((i & 7) << 4));
        gload_lds16(src, (char*)Xs + i * 1024);     // dest: uniform base + lane*16
    }

    // bias regs (L2-hot) — independent of staging, loads overlap drain
    const int col_lo = lane & 15, kgrp = lane >> 4;
    float bias[4];
#pragma unroll
    for (int ct = 0; ct < 4; ++ct) bias[ct] = bm[ct * 16 + col_lo];

    asm volatile("s_waitcnt vmcnt(0)" ::: "memory");
    __builtin_amdgcn_sched_barrier(0);

    // 2. MFMA: A-fragments from LDS (swizzled), B from global/L2
    const int r = lane & 15;
    const int swz = (r & 7) << 4;
    const char* rbase = (const char*)Xs + r * 1024;
    f32x4 acc[4] = {};
#pragma unroll
    for (int kc = 0; kc < 8; ++kc) {
        const int g0 = kgrp * 32 + kc * 128;
        const f32x4 x0 = *(const f32x4*)(rbase + ((g0) ^ swz));
        const f32x4 x1 = *(const f32x4*)(rbase + ((g0 + 16) ^ swz));
        short8 a;
        a[0] = (short)f2bf(x0[0]); a[1] = (short)f2bf(x0[1]);
        a[2] = (short)f2bf(x0[2]); a[3] = (short)f2bf(x0[3]);
        a[4] = (short)f2bf(x1[0]); a[5] = (short)f2bf(x1[1]);
        a[6] = (short)f2bf(x1[2]); a[7] = (short)f2bf(x1[3]);
#pragma unroll
        for (int ct = 0; ct < 4; ++ct) {
            const short8 b = *(const short8*)&Bf[((ct * 8 + kc) * 64 + lane) * 8];
            acc[ct] = __builtin_amdgcn_mfma_f32_16x16x32_bf16(a, b, acc[ct], 0, 0, 0);
        }
    }

    // 3. epilogue: C/D layout col = lane&15, row = (lane>>4)*4 + reg  [m89]
    const int orow0 = rowbase + kgrp * 4;
#pragma unroll
    for (int ct = 0; ct < 4; ++ct) {
        const int col = ct * 16 + col_lo;
#pragma unroll
        for (int rr = 0; rr < 4; ++rr) {
            const int row = orow0 + rr;
            if (row < N)
                out[(size_t)row * 64 + col] = acc[ct][rr] + bias[ct];
        }
    }
}

extern "C" void kernel_launch(void* const* d_in, const int* in_sizes, int n_in,
                              void* d_out, int out_size, void* d_ws, size_t ws_size,
                              hipStream_t stream)
{
    const float* sx = (const float*)d_in[1];        // source_input
    const float* Wv = (const float*)d_in[6];
    const float* bv = (const float*)d_in[7];
    float* out = (float*)d_out;

    unsigned short* Bf = (unsigned short*)d_ws;                 // 32 KB
    float* bm = (float*)((char*)d_ws + 16384 * sizeof(unsigned short));

    const int N = in_sizes[0] / 256;
    const int ntiles = (N + 15) / 16;

    k_prep<<<64, 256, 0, stream>>>(Wv, bv, Bf, bm);
    k_vmean<<<ntiles, 64, 0, stream>>>(sx, Bf, bm, out, N);
}

// Round 9
// 33.577 us; speedup vs baseline: 2.1631x; 1.0608x over previous
//
#include <hip/hip_runtime.h>
#include <hip/hip_bf16.h>

typedef short short8 __attribute__((ext_vector_type(8)));
typedef float f32x4 __attribute__((ext_vector_type(4)));

__device__ inline unsigned short f2bf(float f) {
    unsigned u = __builtin_bit_cast(unsigned, f);
    u += 0x7FFFu + ((u >> 16) & 1u);          // round-to-nearest-even
    return (unsigned short)(u >> 16);
}

// ---------------------------------------------------------------------------
// prep: Wm[d][c] = 0.25 * sum_h Wv[h*64+d][c], packed in MFMA B-fragment order:
//   Bf[((ct*8+kc)*64 + lane)*8 + j] = bf16(Wm[ct*16 + lane%16][kc*32 + (lane/16)*8 + j])
// bm[d] = 0.25 * sum_h bv[h*64+d]
// ---------------------------------------------------------------------------
__global__ __launch_bounds__(256)
void k_prep(const float* __restrict__ Wv, const float* __restrict__ bv,
            unsigned short* __restrict__ Bf, float* __restrict__ bm)
{
    const int t = blockIdx.x * 256 + threadIdx.x;   // 0..16383
    const int fi = t >> 9;                          // fragment index 0..31
    const int lane = (t >> 3) & 63;
    const int j = t & 7;
    const int ct = fi >> 3, kc = fi & 7;
    const int d = ct * 16 + (lane & 15);
    const int c = kc * 32 + (lane >> 4) * 8 + j;
    const float s = 0.25f * (Wv[(size_t)d * 256 + c] +
                             Wv[(size_t)(64 + d) * 256 + c] +
                             Wv[(size_t)(128 + d) * 256 + c] +
                             Wv[(size_t)(192 + d) * 256 + c]);
    Bf[t] = f2bf(s);
    if (t < 64)
        bm[t] = 0.25f * (bv[t] + bv[64 + t] + bv[128 + t] + bv[192 + t]);
}

// ---------------------------------------------------------------------------
// main: out[n][d] = sum_c source[n][c] * Wm[d][c] + bm[d]
// 256 threads = 4 waves; block owns 64 rows, wave owns 16 (R3 structure).
// A: direct per-lane global fragments. B: global/L2 (32 KB shared).
// NEW: epilogue bounces acc through a per-wave LDS tile [16][68] (stride 68
// -> conflict-free writes per 16-lane phase, 2-way b128 reads = free) and
// stores 4x global_store_dwordx4 per lane: each instr = contiguous 1 KB
// (full 128 B lines) instead of 16 scattered 4 B stores -> kills the 2.4x
// WRITE_SIZE inflation seen in round 6 (61 MB vs 25.6 ideal).
// ---------------------------------------------------------------------------
__global__ __launch_bounds__(256)
void k_vmean(const float* __restrict__ X, const unsigned short* __restrict__ Bf,
             const float* __restrict__ bm, float* __restrict__ out, int N)
{
    __shared__ float Xt[4][16 * 68];                // 4 x 4352 B (wave-private)

    const int t = threadIdx.x;
    const int wave = t >> 6, lane = t & 63;
    const int col_lo = lane & 15, kgrp = lane >> 4;
    const int rowbase = blockIdx.x * 64 + wave * 16;

    const int arow0 = rowbase + (lane & 15);
    const int arow = arow0 < N ? arow0 : N - 1;     // clamp tail rows
    const float* xrow = X + (size_t)arow * 256 + kgrp * 8;

    // issue all 16 X loads (8 K-chunks x 32 B per lane) up front
    f32x4 a0[8], a1[8];
#pragma unroll
    for (int kc = 0; kc < 8; ++kc) {
        a0[kc] = *(const f32x4*)(xrow + kc * 32);
        a1[kc] = *(const f32x4*)(xrow + kc * 32 + 4);
    }

    // bias regs (L2-hot, tiny)
    float bias[4];
#pragma unroll
    for (int ct = 0; ct < 4; ++ct) bias[ct] = bm[ct * 16 + col_lo];

    f32x4 acc[4] = {};
#pragma unroll
    for (int kc = 0; kc < 8; ++kc) {
        short8 a;
        a[0] = (short)f2bf(a0[kc][0]); a[1] = (short)f2bf(a0[kc][1]);
        a[2] = (short)f2bf(a0[kc][2]); a[3] = (short)f2bf(a0[kc][3]);
        a[4] = (short)f2bf(a1[kc][0]); a[5] = (short)f2bf(a1[kc][1]);
        a[6] = (short)f2bf(a1[kc][2]); a[7] = (short)f2bf(a1[kc][3]);
#pragma unroll
        for (int ct = 0; ct < 4; ++ct) {
            const short8 b = *(const short8*)&Bf[((ct * 8 + kc) * 64 + lane) * 8];
            acc[ct] = __builtin_amdgcn_mfma_f32_16x16x32_bf16(a, b, acc[ct], 0, 0, 0);
        }
    }

    // epilogue A: acc -> LDS (C/D layout: col=lane&15, row=(lane>>4)*4+reg)
    float* wtile = &Xt[wave][0];
#pragma unroll
    for (int ct = 0; ct < 4; ++ct) {
#pragma unroll
        for (int r = 0; r < 4; ++r)
            wtile[(kgrp * 4 + r) * 68 + ct * 16 + col_lo] = acc[ct][r] + bias[ct];
    }
    // same-wave LDS dependency only (no barrier); compiler inserts lgkmcnt.

    // epilogue B: coalesced stores — instr s = rows [s*4, s*4+4) x cols [0,64)
    //             = contiguous 1 KB, lane covers bytes s*1024 + lane*16.
#pragma unroll
    for (int s = 0; s < 4; ++s) {
        const int rho = s * 4 + (lane >> 4);        // row in tile
        const int c4 = lane & 15;                   // col/4
        const f32x4 v = *(const f32x4*)&wtile[rho * 68 + c4 * 4];
        const int grow = rowbase + rho;
        if (grow < N)
            *(f32x4*)&out[(size_t)grow * 64 + c4 * 4] = v;
    }
}

extern "C" void kernel_launch(void* const* d_in, const int* in_sizes, int n_in,
                              void* d_out, int out_size, void* d_ws, size_t ws_size,
                              hipStream_t stream)
{
    const float* sx = (const float*)d_in[1];        // source_input
    const float* Wv = (const float*)d_in[6];
    const float* bv = (const float*)d_in[7];
    float* out = (float*)d_out;

    unsigned short* Bf = (unsigned short*)d_ws;                 // 32 KB
    float* bm = (float*)((char*)d_ws + 16384 * sizeof(unsigned short));

    const int N = in_sizes[0] / 256;
    const int nblk = (N + 63) / 64;

    k_prep<<<64, 256, 0, stream>>>(Wv, bv, Bf, bm);
    k_vmean<<<nblk, 256, 0, stream>>>(sx, Bf, bm, out, N);
}